// Round 3
// baseline (815.037 us; speedup 1.0000x reference)
//
#include <hip/hip_runtime.h>
#include <cstddef>
#include <cstdint>

#define T_LEN 512
#define O_DIM 4

typedef _Float16 f16x8 __attribute__((ext_vector_type(8)));
typedef float    f32x4 __attribute__((ext_vector_type(4)));

#define MFMA(a, b, c) __builtin_amdgcn_mfma_f32_16x16x32_f16((a), (b), (c), 0, 0, 0)

__device__ __forceinline__ float sigm_f(float x) {
    return __builtin_amdgcn_rcpf(1.0f + __builtin_amdgcn_exp2f(x * -1.44269504f));
}
__device__ __forceinline__ float tanh_f(float x) {
    float e = __builtin_amdgcn_exp2f(x * 2.88539008f);
    return __builtin_fmaf(-2.0f, __builtin_amdgcn_rcpf(e + 1.0f), 1.0f);
}

__device__ __forceinline__ f16x8 zf8() {
    f16x8 r;
#pragma unroll
    for (int j = 0; j < 8; ++j) r[j] = (_Float16)0.0f;
    return r;
}

// B-fragment for 16x16x32 f16 MFMA from a row-major [K x 64] fp32 matrix.
__device__ __forceinline__ f16x8 load_bt(const float* __restrict__ W, int k0, int n) {
    const int lane = threadIdx.x & 63;
    const float* p = W + (size_t)(k0 + ((lane >> 4) << 3)) * 64 + n;
    f16x8 r;
#pragma unroll
    for (int j = 0; j < 8; ++j) r[j] = (_Float16)p[(size_t)j * 64];
    return r;
}

// A-fragment from LDS state array [16][72] f16.
__device__ __forceinline__ f16x8 ld_af(const _Float16* base, int kt) {
    const int lane = threadIdx.x & 63;
    const int m = lane & 15, q = lane >> 4;
    return *(const f16x8*)(base + m * 72 + kt * 32 + q * 8);
}

__global__ __launch_bounds__(256, 1) void ANIMAZeroExact_86887188398421_kernel(
    const float* __restrict__ x,
    const float* __restrict__ Wenc_w, const float* __restrict__ Wenc_b,
    const float* __restrict__ WfW, const float* __restrict__ WfI, const float* __restrict__ WfA,
    const float* __restrict__ Wg_w, const float* __restrict__ Wg_b,
    const float* __restrict__ Iz_w, const float* __restrict__ Iz_b,
    const float* __restrict__ Ir_w, const float* __restrict__ Ir_b,
    const float* __restrict__ Ih_w, const float* __restrict__ Ih_b,
    const float* __restrict__ AfW, const float* __restrict__ AfI, const float* __restrict__ AfA,
    const float* __restrict__ Ag_w, const float* __restrict__ Ag_b,
    const float* __restrict__ phi_w, const float* __restrict__ phi_b,
    float* __restrict__ out)
{
    __shared__ __align__(16) _Float16 Wl[16][72];
    __shared__ __align__(16) _Float16 Il[16][72];
    __shared__ __align__(16) _Float16 Al[16][72];
    __shared__ __align__(16) _Float16 Rl[16][72];
    __shared__ __align__(16) float xtile[16 * 132];
    __shared__ __align__(16) float actb[16 * 64];

    const int tid  = threadIdx.x;
    const int lane = tid & 63;
    const int w    = tid >> 6;
    const int q    = lane >> 4;
    const int c    = lane & 15;
    const int n    = w * 16 + c;
    const int r0   = blockIdx.x * 16;
    const int xr   = tid >> 4, xu = tid & 15;

    for (int i = tid; i < 16 * 72; i += 256) {
        ((_Float16*)Wl)[i] = (_Float16)0.0f;
        ((_Float16*)Il)[i] = (_Float16)0.0f;
        ((_Float16*)Al)[i] = (_Float16)0.0f;
        ((_Float16*)Rl)[i] = (_Float16)0.0f;
    }

    // ---- resident weight B-fragments ----
    f16x8 S1B[6], G1B[4], ZB[6], RB[6], HB[6], AB[6], AGB[4], phiB[2], encB;
#pragma unroll
    for (int j = 0; j < 2; ++j) {
        S1B[j] = load_bt(WfW, 32 * j, n);  S1B[2 + j] = load_bt(WfI, 32 * j, n);  S1B[4 + j] = load_bt(WfA, 32 * j, n);
        AB[j]  = load_bt(AfW, 32 * j, n);  AB[2 + j]  = load_bt(AfI, 32 * j, n);  AB[4 + j]  = load_bt(AfA, 32 * j, n);
    }
#pragma unroll
    for (int j = 0; j < 4; ++j) { G1B[j] = load_bt(Wg_w, 32 * j, n); AGB[j] = load_bt(Ag_w, 32 * j, n); }
#pragma unroll
    for (int j = 0; j < 6; ++j) { ZB[j] = load_bt(Iz_w, 32 * j, n); RB[j] = load_bt(Ir_w, 32 * j, n); HB[j] = load_bt(Ih_w, 32 * j, n); }
#pragma unroll
    for (int j = 0; j < 8; ++j) encB[j] = (q == 0) ? (_Float16)Wenc_w[j * 64 + n] : (_Float16)0.0f;
#pragma unroll
    for (int kt = 0; kt < 2; ++kt)
#pragma unroll
        for (int j = 0; j < 8; ++j) {
            int k = kt * 32 + q * 8 + j;
            phiB[kt][j] = (c < O_DIM && w == 0) ? (_Float16)phi_w[k * O_DIM + c] : (_Float16)0.0f;
        }

    const float bias_g  = Wg_b[n],  bias_z = Iz_b[n], bias_r = Ir_b[n];
    const float bias_h  = Ih_b[n],  bias_ag = Ag_b[n], bias_e = Wenc_b[n];
    const float bias_p  = (c < O_DIM) ? phi_b[c] : 0.0f;

    const float* xgr = x + (size_t)(r0 + xr) * (T_LEN * 8);

    // prologue: x-tile for steps 1..16; xt(0) direct
    {
        int off = 8 + xu * 8;
        if (off > T_LEN * 8 - 8) off = T_LEN * 8 - 8;
        float4 a = *(const float4*)(xgr + off);
        float4 b = *(const float4*)(xgr + off + 4);
        float* d = &xtile[xr * 132 + xu * 8];
        *(float4*)d = a; *(float4*)(d + 4) = b;
    }
    f32x4 zero4 = {0.f, 0.f, 0.f, 0.f};
    float xt[4];
    {
        const float* xrow = x + (size_t)(r0 + c) * (T_LEN * 8);
        float4 a = *(const float4*)(xrow);
        float4 b = *(const float4*)(xrow + 4);
        f16x8 xf;
        float m = (q == 0) ? 1.0f : 0.0f;
        xf[0] = (_Float16)(a.x * m); xf[1] = (_Float16)(a.y * m); xf[2] = (_Float16)(a.z * m); xf[3] = (_Float16)(a.w * m);
        xf[4] = (_Float16)(b.x * m); xf[5] = (_Float16)(b.y * m); xf[6] = (_Float16)(b.z * m); xf[7] = (_Float16)(b.w * m);
        f32x4 e0 = MFMA(xf, encB, zero4);
#pragma unroll
        for (int i = 0; i < 4; ++i) xt[i] = tanh_f(e0[i] + bias_e);
    }

    // cross-stage accumulators (set in stage 4 of previous step / prologue)
    f32x4 w_a = zero4, w_b = zero4, g_a = zero4, g_b = zero4;
    f32x4 zp_a = zero4, zp_c = zero4, rp_a = zero4, rp_c = zero4;
    f32x4 hp_a, hp_c, ap_a, ap_c, ag_a, ag_c;
    float Iv[4] = {0.f, 0.f, 0.f, 0.f};
    f16x8 nW0, nW1;

    __syncthreads();

#pragma unroll 1
    for (int t = 0; t < T_LEN; ++t) {
        const bool fl = ((t & 15) == 0) && (t > 0);

        // ============ stage 1: W_new ============
        f16x8 sA0 = ld_af(&Al[0][0], 0), sA1 = ld_af(&Al[0][0], 1);

        float4 xla, xlb;
        if (fl) {   // issue flush-period global loads right after a barrier (max distance to drain)
            int off = (t + 1) * 8 + xu * 8;
            if (off > T_LEN * 8 - 8) off = T_LEN * 8 - 8;
            xla = *(const float4*)(xgr + off);
            xlb = *(const float4*)(xgr + off + 4);
        }

        // critical: only the 4 A-dependent MFMAs precede the W_new write
        w_a = MFMA(sA0, S1B[4], w_a);  w_b = MFMA(sA1, S1B[5], w_b);
        g_a = MFMA(sA0, G1B[2], g_a);  g_b = MFMA(sA1, G1B[3], g_b);
#pragma unroll
        for (int i = 0; i < 4; ++i) {
            float wn = tanh_f(xt[i] + w_a[i] + w_b[i]) * sigm_f(g_a[i] + g_b[i] + bias_g);
            Wl[4 * q + i][n] = (_Float16)wn;
        }
        // off-path: A-parts of z/r/h; action(t-1)
        zp_a = MFMA(sA0, ZB[4], zp_a);  zp_c = MFMA(sA1, ZB[5], zp_c);
        rp_a = MFMA(sA0, RB[4], rp_a);  rp_c = MFMA(sA1, RB[5], rp_c);
        hp_a = MFMA(sA0, HB[4], zero4); hp_c = MFMA(sA1, HB[5], zero4);
        if (w == 0) {
            f32x4 act = MFMA(sA0, phiB[0], zero4);
            act = MFMA(sA1, phiB[1], act);
            if (t > 0 && c < O_DIM) {
                int sl = (t - 1) & 15;
#pragma unroll
                for (int i = 0; i < 4; ++i) actb[(4 * q + i) * 64 + sl * 4 + c] = act[i] + bias_p;
            }
        }
        __syncthreads();  // alpha

        // ============ stage 2: r*I (and z) ============
        if (fl) {
            float* d = &xtile[xr * 132 + xu * 8];
            *(float4*)d = xla; *(float4*)(d + 4) = xlb;
            float4 av = *(const float4*)(&actb[xr * 64 + xu * 4]);
            *(float4*)(out + (size_t)(r0 + xr) * (T_LEN * O_DIM) + (t - 16 + xu) * 4) = av;
        }
        nW0 = ld_af(&Wl[0][0], 0); nW1 = ld_af(&Wl[0][0], 1);
        // critical
        rp_a = MFMA(nW0, RB[0], rp_a);  rp_c = MFMA(nW1, RB[1], rp_c);
#pragma unroll
        for (int i = 0; i < 4; ++i) {
            float rv = sigm_f(rp_a[i] + rp_c[i] + bias_r);
            Rl[4 * q + i][n] = (_Float16)(rv * Iv[i]);
        }
        // off-path
        zp_a = MFMA(nW0, ZB[0], zp_a);  zp_c = MFMA(nW1, ZB[1], zp_c);
        float zv[4];
#pragma unroll
        for (int i = 0; i < 4; ++i) zv[i] = sigm_f(zp_a[i] + zp_c[i] + bias_z);
        hp_a = MFMA(nW0, HB[0], hp_a);  hp_c = MFMA(nW1, HB[1], hp_c);
        ap_a = MFMA(sA0, AB[4], zero4); ap_c = MFMA(sA1, AB[5], zero4);
        ap_a = MFMA(nW0, AB[0], ap_a);  ap_c = MFMA(nW1, AB[1], ap_c);
        ag_a = MFMA(nW0, AGB[0], zero4); ag_c = MFMA(nW1, AGB[1], zero4);
        __syncthreads();  // beta

        // ============ stage 3: I_new ============
        f16x8 hR0 = ld_af(&Rl[0][0], 0), hR1 = ld_af(&Rl[0][0], 1);
        // critical
        hp_a = MFMA(hR0, HB[2], hp_a);  hp_c = MFMA(hR1, HB[3], hp_c);
#pragma unroll
        for (int i = 0; i < 4; ++i) {
            float hv = tanh_f(hp_a[i] + hp_c[i] + bias_h);
            Iv[i] = __builtin_fmaf(zv[i], hv - Iv[i], Iv[i]);
            Il[4 * q + i][n] = (_Float16)Iv[i];
        }
        // off-path: enc(t+1)
        {
            const float* xs = &xtile[c * 132 + (t & 15) * 8];
            float4 qa = *(const float4*)xs;
            float4 qb = *(const float4*)(xs + 4);
            f16x8 xf;
            float m = (q == 0) ? 1.0f : 0.0f;
            xf[0] = (_Float16)(qa.x * m); xf[1] = (_Float16)(qa.y * m); xf[2] = (_Float16)(qa.z * m); xf[3] = (_Float16)(qa.w * m);
            xf[4] = (_Float16)(qb.x * m); xf[5] = (_Float16)(qb.y * m); xf[6] = (_Float16)(qb.z * m); xf[7] = (_Float16)(qb.w * m);
            f32x4 ep = MFMA(xf, encB, zero4);
#pragma unroll
            for (int i = 0; i < 4; ++i) xt[i] = tanh_f(ep[i] + bias_e);
        }
        __syncthreads();  // gamma

        // ============ stage 4: A_new (+ next-step partials) ============
        f16x8 nI0 = ld_af(&Il[0][0], 0), nI1 = ld_af(&Il[0][0], 1);
        // critical
        ap_a = MFMA(nI0, AB[2], ap_a);  ap_c = MFMA(nI1, AB[3], ap_c);
        ag_a = MFMA(nI0, AGB[2], ag_a); ag_c = MFMA(nI1, AGB[3], ag_c);
#pragma unroll
        for (int i = 0; i < 4; ++i) {
            float av = tanh_f(ap_a[i] + ap_c[i]) * sigm_f(ag_a[i] + ag_c[i] + bias_ag);
            Al[4 * q + i][n] = (_Float16)av;
        }
        // off-path: next step's W/I-based partials (sW=nW, sI=nI)
        w_a = MFMA(nW0, S1B[0], zero4);  w_b = MFMA(nW1, S1B[1], zero4);
        w_a = MFMA(nI0, S1B[2], w_a);    w_b = MFMA(nI1, S1B[3], w_b);
        g_a = MFMA(nI0, G1B[0], zero4);  g_b = MFMA(nI1, G1B[1], zero4);
        zp_a = MFMA(nI0, ZB[2], zero4);  zp_c = MFMA(nI1, ZB[3], zero4);
        rp_a = MFMA(nI0, RB[2], zero4);  rp_c = MFMA(nI1, RB[3], zero4);
        __syncthreads();  // delta
    }

    // epilogue: action(511) + final flush (496..511)
    {
        f16x8 eA0 = ld_af(&Al[0][0], 0), eA1 = ld_af(&Al[0][0], 1);
        if (w == 0) {
            f32x4 act = MFMA(eA0, phiB[0], zero4);
            act = MFMA(eA1, phiB[1], act);
            if (c < O_DIM) {
#pragma unroll
                for (int i = 0; i < 4; ++i) actb[(4 * q + i) * 64 + 15 * 4 + c] = act[i] + bias_p;
            }
        }
        __syncthreads();
        float4 av = *(const float4*)(&actb[xr * 64 + xu * 4]);
        *(float4*)(out + (size_t)(r0 + xr) * (T_LEN * O_DIM) + (496 + xu) * 4) = av;
    }
}

extern "C" void kernel_launch(void* const* d_in, const int* in_sizes, int n_in,
                              void* d_out, int out_size, void* d_ws, size_t ws_size,
                              hipStream_t stream) {
    ANIMAZeroExact_86887188398421_kernel<<<dim3(64), dim3(256), 0, stream>>>(
        (const float*)d_in[0],
        (const float*)d_in[1],  (const float*)d_in[2],
        (const float*)d_in[3],  (const float*)d_in[4],  (const float*)d_in[5],
        (const float*)d_in[6],  (const float*)d_in[7],
        (const float*)d_in[8],  (const float*)d_in[9],
        (const float*)d_in[10], (const float*)d_in[11],
        (const float*)d_in[12], (const float*)d_in[13],
        (const float*)d_in[14], (const float*)d_in[15], (const float*)d_in[16],
        (const float*)d_in[17], (const float*)d_in[18],
        (const float*)d_in[19], (const float*)d_in[20],
        (float*)d_out);
}

// Round 4
// 797.556 us; speedup vs baseline: 1.0219x; 1.0219x over previous
//
#include <hip/hip_runtime.h>
#include <cstddef>
#include <cstdint>

#define T_LEN 512
#define O_DIM 4
#define ROWS 2   // valid batch rows per block (M=16 tile, junk rows are batch-independent)

typedef _Float16 f16x8 __attribute__((ext_vector_type(8)));
typedef float    f32x4 __attribute__((ext_vector_type(4)));

#define MFMA(a, b, c) __builtin_amdgcn_mfma_f32_16x16x32_f16((a), (b), (c), 0, 0, 0)

__device__ __forceinline__ float sigm_f(float x) {
    return __builtin_amdgcn_rcpf(1.0f + __builtin_amdgcn_exp2f(x * -1.44269504f));
}
__device__ __forceinline__ float tanh_f(float x) {
    float e = __builtin_amdgcn_exp2f(x * 2.88539008f);
    return __builtin_fmaf(-2.0f, __builtin_amdgcn_rcpf(e + 1.0f), 1.0f);
}

__device__ __forceinline__ f16x8 zf8() {
    f16x8 r;
#pragma unroll
    for (int j = 0; j < 8; ++j) r[j] = (_Float16)0.0f;
    return r;
}

// B-fragment for 16x16x32 f16 MFMA from a row-major [K x 64] fp32 matrix.
__device__ __forceinline__ f16x8 load_bt(const float* __restrict__ W, int k0, int n) {
    const int lane = threadIdx.x & 63;
    const float* p = W + (size_t)(k0 + ((lane >> 4) << 3)) * 64 + n;
    f16x8 r;
#pragma unroll
    for (int j = 0; j < 8; ++j) r[j] = (_Float16)p[(size_t)j * 64];
    return r;
}

// A-fragment from LDS state array [16][72] f16.
__device__ __forceinline__ f16x8 ld_af(const _Float16* base, int kt) {
    const int lane = threadIdx.x & 63;
    const int m = lane & 15, q = lane >> 4;
    return *(const f16x8*)(base + m * 72 + kt * 32 + q * 8);
}

__global__ __launch_bounds__(256, 2) void ANIMAZeroExact_86887188398421_kernel(
    const float* __restrict__ x,
    const float* __restrict__ Wenc_w, const float* __restrict__ Wenc_b,
    const float* __restrict__ WfW, const float* __restrict__ WfI, const float* __restrict__ WfA,
    const float* __restrict__ Wg_w, const float* __restrict__ Wg_b,
    const float* __restrict__ Iz_w, const float* __restrict__ Iz_b,
    const float* __restrict__ Ir_w, const float* __restrict__ Ir_b,
    const float* __restrict__ Ih_w, const float* __restrict__ Ih_b,
    const float* __restrict__ AfW, const float* __restrict__ AfI, const float* __restrict__ AfA,
    const float* __restrict__ Ag_w, const float* __restrict__ Ag_b,
    const float* __restrict__ phi_w, const float* __restrict__ phi_b,
    float* __restrict__ out)
{
    __shared__ __align__(16) _Float16 Wl[16][72];
    __shared__ __align__(16) _Float16 Il[16][72];
    __shared__ __align__(16) _Float16 Al[16][72];
    __shared__ __align__(16) _Float16 Rl[16][72];
    __shared__ __align__(16) float xtile[16 * 132];
    __shared__ __align__(16) float actb[16 * 64];

    const int tid  = threadIdx.x;
    const int lane = tid & 63;
    const int w    = tid >> 6;
    const int q    = lane >> 4;
    const int c    = lane & 15;
    const int n    = w * 16 + c;
    const int r0   = blockIdx.x * ROWS;
    const int xr   = tid >> 4, xu = tid & 15;
    const int xrc  = (xr < ROWS) ? xr : (ROWS - 1);   // clamped source row for x staging

    for (int i = tid; i < 16 * 72; i += 256) {
        ((_Float16*)Wl)[i] = (_Float16)0.0f;
        ((_Float16*)Il)[i] = (_Float16)0.0f;
        ((_Float16*)Al)[i] = (_Float16)0.0f;
        ((_Float16*)Rl)[i] = (_Float16)0.0f;
    }

    // ---- resident weight B-fragments ----
    f16x8 S1B[6], G1B[4], ZB[6], RB[6], HB[6], AB[6], AGB[4], phiB[2], encB;
#pragma unroll
    for (int j = 0; j < 2; ++j) {
        S1B[j] = load_bt(WfW, 32 * j, n);  S1B[2 + j] = load_bt(WfI, 32 * j, n);  S1B[4 + j] = load_bt(WfA, 32 * j, n);
        AB[j]  = load_bt(AfW, 32 * j, n);  AB[2 + j]  = load_bt(AfI, 32 * j, n);  AB[4 + j]  = load_bt(AfA, 32 * j, n);
    }
#pragma unroll
    for (int j = 0; j < 4; ++j) { G1B[j] = load_bt(Wg_w, 32 * j, n); AGB[j] = load_bt(Ag_w, 32 * j, n); }
#pragma unroll
    for (int j = 0; j < 6; ++j) { ZB[j] = load_bt(Iz_w, 32 * j, n); RB[j] = load_bt(Ir_w, 32 * j, n); HB[j] = load_bt(Ih_w, 32 * j, n); }
#pragma unroll
    for (int j = 0; j < 8; ++j) encB[j] = (q == 0) ? (_Float16)Wenc_w[j * 64 + n] : (_Float16)0.0f;
#pragma unroll
    for (int kt = 0; kt < 2; ++kt)
#pragma unroll
        for (int j = 0; j < 8; ++j) {
            int k = kt * 32 + q * 8 + j;
            phiB[kt][j] = (c < O_DIM && w == 0) ? (_Float16)phi_w[k * O_DIM + c] : (_Float16)0.0f;
        }

    const float bias_g  = Wg_b[n],  bias_z = Iz_b[n], bias_r = Ir_b[n];
    const float bias_h  = Ih_b[n],  bias_ag = Ag_b[n], bias_e = Wenc_b[n];
    const float bias_p  = (c < O_DIM) ? phi_b[c] : 0.0f;

    const float* xgr = x + (size_t)(r0 + xrc) * (T_LEN * 8);

    // prologue: x-tile for steps 1..16 (junk rows duplicate last valid row); xt(0) direct
    {
        int off = 8 + xu * 8;
        if (off > T_LEN * 8 - 8) off = T_LEN * 8 - 8;
        float4 a = *(const float4*)(xgr + off);
        float4 b = *(const float4*)(xgr + off + 4);
        float* d = &xtile[xr * 132 + xu * 8];
        *(float4*)d = a; *(float4*)(d + 4) = b;
    }
    f32x4 zero4 = {0.f, 0.f, 0.f, 0.f};
    float xt[ROWS];
    {
        const int cc = (c < ROWS) ? c : (ROWS - 1);
        const float* xrow = x + (size_t)(r0 + cc) * (T_LEN * 8);
        float4 a = *(const float4*)(xrow);
        float4 b = *(const float4*)(xrow + 4);
        f16x8 xf;
        float m = (q == 0) ? 1.0f : 0.0f;
        xf[0] = (_Float16)(a.x * m); xf[1] = (_Float16)(a.y * m); xf[2] = (_Float16)(a.z * m); xf[3] = (_Float16)(a.w * m);
        xf[4] = (_Float16)(b.x * m); xf[5] = (_Float16)(b.y * m); xf[6] = (_Float16)(b.z * m); xf[7] = (_Float16)(b.w * m);
        f32x4 e0 = MFMA(xf, encB, zero4);
#pragma unroll
        for (int i = 0; i < ROWS; ++i) xt[i] = tanh_f(e0[i] + bias_e);
    }

    // cross-stage accumulators
    f32x4 w_a = zero4, w_b = zero4, g_a = zero4, g_b = zero4;
    f32x4 zp_a = zero4, zp_c = zero4, rp_a = zero4, rp_c = zero4;
    f32x4 hp_a, hp_c, ap_a, ap_c, ag_a, ag_c;
    float Iv[ROWS] = {0.f, 0.f};
    f16x8 nW0, nW1;

    __syncthreads();

#pragma unroll 1
    for (int t = 0; t < T_LEN; ++t) {
        const bool fl = ((t & 15) == 0) && (t > 0);

        // ============ stage 1: W_new ============
        f16x8 sA0 = ld_af(&Al[0][0], 0), sA1 = ld_af(&Al[0][0], 1);

        float4 xla, xlb;
        if (fl) {
            int off = (t + 1) * 8 + xu * 8;
            if (off > T_LEN * 8 - 8) off = T_LEN * 8 - 8;
            xla = *(const float4*)(xgr + off);
            xlb = *(const float4*)(xgr + off + 4);
        }

        w_a = MFMA(sA0, S1B[4], w_a);  w_b = MFMA(sA1, S1B[5], w_b);
        g_a = MFMA(sA0, G1B[2], g_a);  g_b = MFMA(sA1, G1B[3], g_b);
#pragma unroll
        for (int i = 0; i < ROWS; ++i) {
            float wn = tanh_f(xt[i] + w_a[i] + w_b[i]) * sigm_f(g_a[i] + g_b[i] + bias_g);
            Wl[4 * q + i][n] = (_Float16)wn;
        }
        zp_a = MFMA(sA0, ZB[4], zp_a);  zp_c = MFMA(sA1, ZB[5], zp_c);
        rp_a = MFMA(sA0, RB[4], rp_a);  rp_c = MFMA(sA1, RB[5], rp_c);
        hp_a = MFMA(sA0, HB[4], zero4); hp_c = MFMA(sA1, HB[5], zero4);
        if (w == 0) {
            f32x4 act = MFMA(sA0, phiB[0], zero4);
            act = MFMA(sA1, phiB[1], act);
            if (t > 0 && c < O_DIM) {
                int sl = (t - 1) & 15;
#pragma unroll
                for (int i = 0; i < ROWS; ++i) actb[(4 * q + i) * 64 + sl * 4 + c] = act[i] + bias_p;
            }
        }
        __syncthreads();  // alpha

        // ============ stage 2: r*I (and z) ============
        if (fl) {
            float* d = &xtile[xr * 132 + xu * 8];
            *(float4*)d = xla; *(float4*)(d + 4) = xlb;
            if (xr < ROWS) {
                float4 av = *(const float4*)(&actb[xr * 64 + xu * 4]);
                *(float4*)(out + (size_t)(r0 + xr) * (T_LEN * O_DIM) + (t - 16 + xu) * 4) = av;
            }
        }
        nW0 = ld_af(&Wl[0][0], 0); nW1 = ld_af(&Wl[0][0], 1);
        rp_a = MFMA(nW0, RB[0], rp_a);  rp_c = MFMA(nW1, RB[1], rp_c);
#pragma unroll
        for (int i = 0; i < ROWS; ++i) {
            float rv = sigm_f(rp_a[i] + rp_c[i] + bias_r);
            Rl[4 * q + i][n] = (_Float16)(rv * Iv[i]);
        }
        zp_a = MFMA(nW0, ZB[0], zp_a);  zp_c = MFMA(nW1, ZB[1], zp_c);
        float zv[ROWS];
#pragma unroll
        for (int i = 0; i < ROWS; ++i) zv[i] = sigm_f(zp_a[i] + zp_c[i] + bias_z);
        hp_a = MFMA(nW0, HB[0], hp_a);  hp_c = MFMA(nW1, HB[1], hp_c);
        ap_a = MFMA(sA0, AB[4], zero4); ap_c = MFMA(sA1, AB[5], zero4);
        ap_a = MFMA(nW0, AB[0], ap_a);  ap_c = MFMA(nW1, AB[1], ap_c);
        ag_a = MFMA(nW0, AGB[0], zero4); ag_c = MFMA(nW1, AGB[1], zero4);
        __syncthreads();  // beta

        // ============ stage 3: I_new ============
        f16x8 hR0 = ld_af(&Rl[0][0], 0), hR1 = ld_af(&Rl[0][0], 1);
        hp_a = MFMA(hR0, HB[2], hp_a);  hp_c = MFMA(hR1, HB[3], hp_c);
#pragma unroll
        for (int i = 0; i < ROWS; ++i) {
            float hv = tanh_f(hp_a[i] + hp_c[i] + bias_h);
            Iv[i] = __builtin_fmaf(zv[i], hv - Iv[i], Iv[i]);
            Il[4 * q + i][n] = (_Float16)Iv[i];
        }
        // off-path: enc(t+1)
        {
            const float* xs = &xtile[c * 132 + (t & 15) * 8];
            float4 qa = *(const float4*)xs;
            float4 qb = *(const float4*)(xs + 4);
            f16x8 xf;
            float m = (q == 0) ? 1.0f : 0.0f;
            xf[0] = (_Float16)(qa.x * m); xf[1] = (_Float16)(qa.y * m); xf[2] = (_Float16)(qa.z * m); xf[3] = (_Float16)(qa.w * m);
            xf[4] = (_Float16)(qb.x * m); xf[5] = (_Float16)(qb.y * m); xf[6] = (_Float16)(qb.z * m); xf[7] = (_Float16)(qb.w * m);
            f32x4 ep = MFMA(xf, encB, zero4);
#pragma unroll
            for (int i = 0; i < ROWS; ++i) xt[i] = tanh_f(ep[i] + bias_e);
        }
        __syncthreads();  // gamma

        // ============ stage 4: A_new (+ next-step partials) ============
        f16x8 nI0 = ld_af(&Il[0][0], 0), nI1 = ld_af(&Il[0][0], 1);
        ap_a = MFMA(nI0, AB[2], ap_a);  ap_c = MFMA(nI1, AB[3], ap_c);
        ag_a = MFMA(nI0, AGB[2], ag_a); ag_c = MFMA(nI1, AGB[3], ag_c);
#pragma unroll
        for (int i = 0; i < ROWS; ++i) {
            float av = tanh_f(ap_a[i] + ap_c[i]) * sigm_f(ag_a[i] + ag_c[i] + bias_ag);
            Al[4 * q + i][n] = (_Float16)av;
        }
        w_a = MFMA(nW0, S1B[0], zero4);  w_b = MFMA(nW1, S1B[1], zero4);
        w_a = MFMA(nI0, S1B[2], w_a);    w_b = MFMA(nI1, S1B[3], w_b);
        g_a = MFMA(nI0, G1B[0], zero4);  g_b = MFMA(nI1, G1B[1], zero4);
        zp_a = MFMA(nI0, ZB[2], zero4);  zp_c = MFMA(nI1, ZB[3], zero4);
        rp_a = MFMA(nI0, RB[2], zero4);  rp_c = MFMA(nI1, RB[3], zero4);
        __syncthreads();  // delta
    }

    // epilogue: action(511) + final flush (496..511)
    {
        f16x8 eA0 = ld_af(&Al[0][0], 0), eA1 = ld_af(&Al[0][0], 1);
        if (w == 0) {
            f32x4 act = MFMA(eA0, phiB[0], zero4);
            act = MFMA(eA1, phiB[1], act);
            if (c < O_DIM) {
#pragma unroll
                for (int i = 0; i < ROWS; ++i) actb[(4 * q + i) * 64 + 15 * 4 + c] = act[i] + bias_p;
            }
        }
        __syncthreads();
        if (xr < ROWS) {
            float4 av = *(const float4*)(&actb[xr * 64 + xu * 4]);
            *(float4*)(out + (size_t)(r0 + xr) * (T_LEN * O_DIM) + (496 + xu) * 4) = av;
        }
    }
}

extern "C" void kernel_launch(void* const* d_in, const int* in_sizes, int n_in,
                              void* d_out, int out_size, void* d_ws, size_t ws_size,
                              hipStream_t stream) {
    ANIMAZeroExact_86887188398421_kernel<<<dim3(512), dim3(256), 0, stream>>>(
        (const float*)d_in[0],
        (const float*)d_in[1],  (const float*)d_in[2],
        (const float*)d_in[3],  (const float*)d_in[4],  (const float*)d_in[5],
        (const float*)d_in[6],  (const float*)d_in[7],
        (const float*)d_in[8],  (const float*)d_in[9],
        (const float*)d_in[10], (const float*)d_in[11],
        (const float*)d_in[12], (const float*)d_in[13],
        (const float*)d_in[14], (const float*)d_in[15], (const float*)d_in[16],
        (const float*)d_in[17], (const float*)d_in[18],
        (const float*)d_in[19], (const float*)d_in[20],
        (float*)d_out);
}

// Round 5
// 684.843 us; speedup vs baseline: 1.1901x; 1.1646x over previous
//
#include <hip/hip_runtime.h>
#include <cstddef>
#include <cstdint>

#define T_LEN 512
#define O_DIM 4

typedef _Float16 f16x8 __attribute__((ext_vector_type(8)));
typedef float    f32x4 __attribute__((ext_vector_type(4)));

#define MFMA(a, b, c) __builtin_amdgcn_mfma_f32_16x16x32_f16((a), (b), (c), 0, 0, 0)

__device__ __forceinline__ float sigm_f(float x) {
    return __builtin_amdgcn_rcpf(1.0f + __builtin_amdgcn_exp2f(x * -1.44269504f));
}
__device__ __forceinline__ float tanh_f(float x) {
    float e = __builtin_amdgcn_exp2f(x * 2.88539008f);
    return __builtin_fmaf(-2.0f, __builtin_amdgcn_rcpf(e + 1.0f), 1.0f);
}

// B-fragment for 16x16x32 f16 MFMA from a row-major [K x 64] fp32 matrix.
__device__ __forceinline__ f16x8 load_bt(const float* __restrict__ W, int k0, int n) {
    const int lane = threadIdx.x & 63;
    const float* p = W + (size_t)(k0 + ((lane >> 4) << 3)) * 64 + n;
    f16x8 r;
#pragma unroll
    for (int j = 0; j < 8; ++j) r[j] = (_Float16)p[(size_t)j * 64];
    return r;
}

// A-fragment from LDS state array [16][72] f16.
__device__ __forceinline__ f16x8 ld_af(const _Float16* base, int kt) {
    const int lane = threadIdx.x & 63;
    const int m = lane & 15, q = lane >> 4;
    return *(const f16x8*)(base + m * 72 + kt * 32 + q * 8);
}

// Block = 512 threads = two independent 2-row groups (waves 0-3 = group 0,
// waves 4-7 = group 1). Waves w and w+4 share a SIMD: two independent
// dependency chains per barrier segment -> deterministic latency overlap.
// Valid batch rows sit at tile rows {0,4} (i.e. 4q for q<2): each lane runs
// ONE activation set per stage instead of two.
__global__ __launch_bounds__(512, 1) void ANIMAZeroExact_86887188398421_kernel(
    const float* __restrict__ x,
    const float* __restrict__ Wenc_w, const float* __restrict__ Wenc_b,
    const float* __restrict__ WfW, const float* __restrict__ WfI, const float* __restrict__ WfA,
    const float* __restrict__ Wg_w, const float* __restrict__ Wg_b,
    const float* __restrict__ Iz_w, const float* __restrict__ Iz_b,
    const float* __restrict__ Ir_w, const float* __restrict__ Ir_b,
    const float* __restrict__ Ih_w, const float* __restrict__ Ih_b,
    const float* __restrict__ AfW, const float* __restrict__ AfI, const float* __restrict__ AfA,
    const float* __restrict__ Ag_w, const float* __restrict__ Ag_b,
    const float* __restrict__ phi_w, const float* __restrict__ phi_b,
    float* __restrict__ out)
{
    __shared__ __align__(16) _Float16 Wl[2][16][72];
    __shared__ __align__(16) _Float16 Il[2][16][72];
    __shared__ __align__(16) _Float16 Al[2][16][72];
    __shared__ __align__(16) _Float16 Rl[2][16][72];
    __shared__ __align__(16) float xtile[2][2][136];   // [group][batch row][slot*8]
    __shared__ __align__(16) float actb[2][2][16][4];  // [group][batch row][slot][o]

    const int tid  = threadIdx.x;
    const int g    = tid >> 8;        // group 0/1
    const int tl   = tid & 255;       // id within group
    const int w    = tl >> 6;         // wave within group, 0..3
    const int lane = tid & 63;
    const int q    = lane >> 4;
    const int c    = lane & 15;
    const int n    = w * 16 + c;
    const int r0   = blockIdx.x * 4 + g * 2;   // 2 batch rows per group
    const int sr   = tl >> 4, su = tl & 15;    // stage/flush mapping (tl<32 only)

    _Float16* WlG = &Wl[g][0][0];
    _Float16* IlG = &Il[g][0][0];
    _Float16* AlG = &Al[g][0][0];
    _Float16* RlG = &Rl[g][0][0];

    // zero all state rows once; junk rows (not 4q) stay zero forever
    for (int i = tl; i < 16 * 72; i += 256) {
        WlG[i] = (_Float16)0.0f; IlG[i] = (_Float16)0.0f;
        AlG[i] = (_Float16)0.0f; RlG[i] = (_Float16)0.0f;
    }

    // ---- resident weight B-fragments ----
    f16x8 S1B[6], G1B[4], ZB[6], RB[6], HB[6], AB[6], AGB[4], phiB[2], encB;
#pragma unroll
    for (int j = 0; j < 2; ++j) {
        S1B[j] = load_bt(WfW, 32 * j, n);  S1B[2 + j] = load_bt(WfI, 32 * j, n);  S1B[4 + j] = load_bt(WfA, 32 * j, n);
        AB[j]  = load_bt(AfW, 32 * j, n);  AB[2 + j]  = load_bt(AfI, 32 * j, n);  AB[4 + j]  = load_bt(AfA, 32 * j, n);
    }
#pragma unroll
    for (int j = 0; j < 4; ++j) { G1B[j] = load_bt(Wg_w, 32 * j, n); AGB[j] = load_bt(Ag_w, 32 * j, n); }
#pragma unroll
    for (int j = 0; j < 6; ++j) { ZB[j] = load_bt(Iz_w, 32 * j, n); RB[j] = load_bt(Ir_w, 32 * j, n); HB[j] = load_bt(Ih_w, 32 * j, n); }
#pragma unroll
    for (int j = 0; j < 8; ++j) encB[j] = (q == 0) ? (_Float16)Wenc_w[j * 64 + n] : (_Float16)0.0f;
#pragma unroll
    for (int kt = 0; kt < 2; ++kt)
#pragma unroll
        for (int j = 0; j < 8; ++j) {
            int k = kt * 32 + q * 8 + j;
            phiB[kt][j] = (c < O_DIM && w == 0) ? (_Float16)phi_w[k * O_DIM + c] : (_Float16)0.0f;
        }

    const float bias_g  = Wg_b[n],  bias_z = Iz_b[n], bias_r = Ir_b[n];
    const float bias_h  = Ih_b[n],  bias_ag = Ag_b[n], bias_e = Wenc_b[n];
    const float bias_p  = (c < O_DIM) ? phi_b[c] : 0.0f;

    const float* xgr = x + (size_t)(r0 + sr) * (T_LEN * 8);   // used by tl<32 only

    // prologue: stage x for steps 1..16
    if (tl < 32) {
        int off = (1 + su) * 8;
        float4 a = *(const float4*)(xgr + off);
        float4 b = *(const float4*)(xgr + off + 4);
        float* d = &xtile[g][sr][su * 8];
        *(float4*)d = a; *(float4*)(d + 4) = b;
    }
    f32x4 zero4 = {0.f, 0.f, 0.f, 0.f};
    float xt;
    {
        const int mrow = (c == 0) ? 0 : 1;    // tile row c holds batch row 0 (c==0) else 1 (c==4 valid, rest junk-dup)
        const float* xrow = x + (size_t)(r0 + mrow) * (T_LEN * 8);
        float4 a = *(const float4*)(xrow);
        float4 b = *(const float4*)(xrow + 4);
        f16x8 xf;
        float m = (q == 0) ? 1.0f : 0.0f;
        xf[0] = (_Float16)(a.x * m); xf[1] = (_Float16)(a.y * m); xf[2] = (_Float16)(a.z * m); xf[3] = (_Float16)(a.w * m);
        xf[4] = (_Float16)(b.x * m); xf[5] = (_Float16)(b.y * m); xf[6] = (_Float16)(b.z * m); xf[7] = (_Float16)(b.w * m);
        f32x4 e0 = MFMA(xf, encB, zero4);
        xt = tanh_f(e0[0] + bias_e);
    }

    // cross-stage accumulators
    f32x4 w_a = zero4, w_b = zero4, g_a = zero4, g_b = zero4;
    f32x4 zp_a = zero4, zp_c = zero4, rp_a = zero4, rp_c = zero4;
    f32x4 hp_a, hp_c, ap_a, ap_c, ag_a, ag_c;
    float Iv = 0.f;
    f16x8 nW0, nW1;

    __syncthreads();

#pragma unroll 1
    for (int t = 0; t < T_LEN; ++t) {
        const bool fl = ((t & 15) == 0) && (t > 0);

        // ============ stage 1: W_new ============
        f16x8 sA0 = ld_af(AlG, 0), sA1 = ld_af(AlG, 1);

        float4 xla, xlb;
        if (fl && tl < 32) {
            int off = (t + 1) * 8 + su * 8;
            if (off > T_LEN * 8 - 8) off = T_LEN * 8 - 8;
            xla = *(const float4*)(xgr + off);
            xlb = *(const float4*)(xgr + off + 4);
        }

        w_a = MFMA(sA0, S1B[4], w_a);  w_b = MFMA(sA1, S1B[5], w_b);
        g_a = MFMA(sA0, G1B[2], g_a);  g_b = MFMA(sA1, G1B[3], g_b);
        {
            float wn = tanh_f(xt + w_a[0] + w_b[0]) * sigm_f(g_a[0] + g_b[0] + bias_g);
            WlG[4 * q * 72 + n] = (_Float16)wn;
        }
        zp_a = MFMA(sA0, ZB[4], zp_a);  zp_c = MFMA(sA1, ZB[5], zp_c);
        rp_a = MFMA(sA0, RB[4], rp_a);  rp_c = MFMA(sA1, RB[5], rp_c);
        hp_a = MFMA(sA0, HB[4], zero4); hp_c = MFMA(sA1, HB[5], zero4);
        if (w == 0) {
            f32x4 act = MFMA(sA0, phiB[0], zero4);
            act = MFMA(sA1, phiB[1], act);
            if (t > 0 && c < O_DIM && q < 2)
                actb[g][q][(t - 1) & 15][c] = act[0] + bias_p;
        }
        __syncthreads();  // alpha

        // ============ stage 2: r*I (and z) ============
        if (fl && tl < 32) {
            float* d = &xtile[g][sr][su * 8];
            *(float4*)d = xla; *(float4*)(d + 4) = xlb;
            float4 av = *(const float4*)(&actb[g][sr][su][0]);
            *(float4*)(out + (size_t)(r0 + sr) * (T_LEN * O_DIM) + (t - 16 + su) * 4) = av;
        }
        nW0 = ld_af(WlG, 0); nW1 = ld_af(WlG, 1);
        rp_a = MFMA(nW0, RB[0], rp_a);  rp_c = MFMA(nW1, RB[1], rp_c);
        {
            float rv = sigm_f(rp_a[0] + rp_c[0] + bias_r);
            RlG[4 * q * 72 + n] = (_Float16)(rv * Iv);
        }
        zp_a = MFMA(nW0, ZB[0], zp_a);  zp_c = MFMA(nW1, ZB[1], zp_c);
        float zv = sigm_f(zp_a[0] + zp_c[0] + bias_z);
        hp_a = MFMA(nW0, HB[0], hp_a);  hp_c = MFMA(nW1, HB[1], hp_c);
        ap_a = MFMA(sA0, AB[4], zero4); ap_c = MFMA(sA1, AB[5], zero4);
        ap_a = MFMA(nW0, AB[0], ap_a);  ap_c = MFMA(nW1, AB[1], ap_c);
        ag_a = MFMA(nW0, AGB[0], zero4); ag_c = MFMA(nW1, AGB[1], zero4);
        __syncthreads();  // beta

        // ============ stage 3: I_new ============
        f16x8 hR0 = ld_af(RlG, 0), hR1 = ld_af(RlG, 1);
        hp_a = MFMA(hR0, HB[2], hp_a);  hp_c = MFMA(hR1, HB[3], hp_c);
        {
            float hv = tanh_f(hp_a[0] + hp_c[0] + bias_h);
            Iv = __builtin_fmaf(zv, hv - Iv, Iv);
            IlG[4 * q * 72 + n] = (_Float16)Iv;
        }
        // off-path: enc(t+1)
        {
            const int mr = (c == 0) ? 0 : 1;
            const float* xs = &xtile[g][mr][(t & 15) * 8];
            float4 qa = *(const float4*)xs;
            float4 qb = *(const float4*)(xs + 4);
            f16x8 xf;
            float m = (q == 0) ? 1.0f : 0.0f;
            xf[0] = (_Float16)(qa.x * m); xf[1] = (_Float16)(qa.y * m); xf[2] = (_Float16)(qa.z * m); xf[3] = (_Float16)(qa.w * m);
            xf[4] = (_Float16)(qb.x * m); xf[5] = (_Float16)(qb.y * m); xf[6] = (_Float16)(qb.z * m); xf[7] = (_Float16)(qb.w * m);
            f32x4 ep = MFMA(xf, encB, zero4);
            xt = tanh_f(ep[0] + bias_e);
        }
        __syncthreads();  // gamma

        // ============ stage 4: A_new (+ next-step partials) ============
        f16x8 nI0 = ld_af(IlG, 0), nI1 = ld_af(IlG, 1);
        ap_a = MFMA(nI0, AB[2], ap_a);  ap_c = MFMA(nI1, AB[3], ap_c);
        ag_a = MFMA(nI0, AGB[2], ag_a); ag_c = MFMA(nI1, AGB[3], ag_c);
        {
            float av = tanh_f(ap_a[0] + ap_c[0]) * sigm_f(ag_a[0] + ag_c[0] + bias_ag);
            AlG[4 * q * 72 + n] = (_Float16)av;
        }
        w_a = MFMA(nW0, S1B[0], zero4);  w_b = MFMA(nW1, S1B[1], zero4);
        w_a = MFMA(nI0, S1B[2], w_a);    w_b = MFMA(nI1, S1B[3], w_b);
        g_a = MFMA(nI0, G1B[0], zero4);  g_b = MFMA(nI1, G1B[1], zero4);
        zp_a = MFMA(nI0, ZB[2], zero4);  zp_c = MFMA(nI1, ZB[3], zero4);
        rp_a = MFMA(nI0, RB[2], zero4);  rp_c = MFMA(nI1, RB[3], zero4);
        __syncthreads();  // delta
    }

    // epilogue: action(511) + final flush (496..511)
    {
        f16x8 eA0 = ld_af(AlG, 0), eA1 = ld_af(AlG, 1);
        if (w == 0) {
            f32x4 act = MFMA(eA0, phiB[0], zero4);
            act = MFMA(eA1, phiB[1], act);
            if (c < O_DIM && q < 2)
                actb[g][q][15][c] = act[0] + bias_p;
        }
        __syncthreads();
        if (tl < 32) {
            float4 av = *(const float4*)(&actb[g][sr][su][0]);
            *(float4*)(out + (size_t)(r0 + sr) * (T_LEN * O_DIM) + (496 + su) * 4) = av;
        }
    }
}

extern "C" void kernel_launch(void* const* d_in, const int* in_sizes, int n_in,
                              void* d_out, int out_size, void* d_ws, size_t ws_size,
                              hipStream_t stream) {
    ANIMAZeroExact_86887188398421_kernel<<<dim3(256), dim3(512), 0, stream>>>(
        (const float*)d_in[0],
        (const float*)d_in[1],  (const float*)d_in[2],
        (const float*)d_in[3],  (const float*)d_in[4],  (const float*)d_in[5],
        (const float*)d_in[6],  (const float*)d_in[7],
        (const float*)d_in[8],  (const float*)d_in[9],
        (const float*)d_in[10], (const float*)d_in[11],
        (const float*)d_in[12], (const float*)d_in[13],
        (const float*)d_in[14], (const float*)d_in[15], (const float*)d_in[16],
        (const float*)d_in[17], (const float*)d_in[18],
        (const float*)d_in[19], (const float*)d_in[20],
        (float*)d_out);
}

// Round 6
// 562.930 us; speedup vs baseline: 1.4478x; 1.2166x over previous
//
#include <hip/hip_runtime.h>
#include <cstddef>
#include <cstdint>

#define T_LEN 512
#define O_DIM 4

typedef _Float16 f16x8 __attribute__((ext_vector_type(8)));
typedef float    f32x4 __attribute__((ext_vector_type(4)));

#define MFMA(a, b, c) __builtin_amdgcn_mfma_f32_16x16x32_f16((a), (b), (c), 0, 0, 0)

__device__ __forceinline__ float sigm_f(float x) {
    return __builtin_amdgcn_rcpf(1.0f + __builtin_amdgcn_exp2f(x * -1.44269504f));
}
__device__ __forceinline__ float tanh_f(float x) {
    float e = __builtin_amdgcn_exp2f(x * 2.88539008f);
    return __builtin_fmaf(-2.0f, __builtin_amdgcn_rcpf(e + 1.0f), 1.0f);
}

// B-fragment for 16x16x32 f16 MFMA from a row-major [K x 64] fp32 matrix.
__device__ __forceinline__ f16x8 load_bt(const float* __restrict__ W, int k0, int n) {
    const int lane = threadIdx.x & 63;
    const float* p = W + (size_t)(k0 + ((lane >> 4) << 3)) * 64 + n;
    f16x8 r;
#pragma unroll
    for (int j = 0; j < 8; ++j) r[j] = (_Float16)p[(size_t)j * 64];
    return r;
}

// A-fragment from LDS state array [16][72] f16.
__device__ __forceinline__ f16x8 ld_af(const _Float16* base, int kt) {
    const int lane = threadIdx.x & 63;
    const int m = lane & 15, q = lane >> 4;
    return *(const f16x8*)(base + m * 72 + kt * 32 + q * 8);
}

// 256 threads = 4 waves (one per SIMD), ONE barrier-phase group per block.
// 4 valid batch rows per block at tile rows {0,4,8,12}: C-layout row = 4q+i,
// so each lane's acc[0] is its own valid row (r0+q) -> 1 activation set/lane,
// and one 38-MFMA set serves 4 rows (halves MFMA issue vs 2-row tiles).
// enc is a per-lane 8-FMA dot (Wenc column in regs) on prefetched x.
__global__ __launch_bounds__(256, 1) void ANIMAZeroExact_86887188398421_kernel(
    const float* __restrict__ x,
    const float* __restrict__ Wenc_w, const float* __restrict__ Wenc_b,
    const float* __restrict__ WfW, const float* __restrict__ WfI, const float* __restrict__ WfA,
    const float* __restrict__ Wg_w, const float* __restrict__ Wg_b,
    const float* __restrict__ Iz_w, const float* __restrict__ Iz_b,
    const float* __restrict__ Ir_w, const float* __restrict__ Ir_b,
    const float* __restrict__ Ih_w, const float* __restrict__ Ih_b,
    const float* __restrict__ AfW, const float* __restrict__ AfI, const float* __restrict__ AfA,
    const float* __restrict__ Ag_w, const float* __restrict__ Ag_b,
    const float* __restrict__ phi_w, const float* __restrict__ phi_b,
    float* __restrict__ out)
{
    __shared__ __align__(16) _Float16 Wl[16][72];
    __shared__ __align__(16) _Float16 Il[16][72];
    __shared__ __align__(16) _Float16 Al[16][72];
    __shared__ __align__(16) _Float16 Rl[16][72];
    __shared__ __align__(16) float actb[4][16][4];   // [row][slot][o]

    const int tid  = threadIdx.x;
    const int w    = tid >> 6;
    const int lane = tid & 63;
    const int q    = lane >> 4;
    const int c    = lane & 15;
    const int n    = w * 16 + c;
    const int r0   = blockIdx.x * 4;

    // zero states; junk tile rows stay zero forever
    for (int i = tid; i < 16 * 72; i += 256) {
        (&Wl[0][0])[i] = (_Float16)0.0f; (&Il[0][0])[i] = (_Float16)0.0f;
        (&Al[0][0])[i] = (_Float16)0.0f; (&Rl[0][0])[i] = (_Float16)0.0f;
    }

    // ---- resident weight B-fragments ----
    f16x8 S1B[6], G1B[4], ZB[6], RB[6], HB[6], AB[6], AGB[4], phiB[2];
#pragma unroll
    for (int j = 0; j < 2; ++j) {
        S1B[j] = load_bt(WfW, 32 * j, n);  S1B[2 + j] = load_bt(WfI, 32 * j, n);  S1B[4 + j] = load_bt(WfA, 32 * j, n);
        AB[j]  = load_bt(AfW, 32 * j, n);  AB[2 + j]  = load_bt(AfI, 32 * j, n);  AB[4 + j]  = load_bt(AfA, 32 * j, n);
    }
#pragma unroll
    for (int j = 0; j < 4; ++j) { G1B[j] = load_bt(Wg_w, 32 * j, n); AGB[j] = load_bt(Ag_w, 32 * j, n); }
#pragma unroll
    for (int j = 0; j < 6; ++j) { ZB[j] = load_bt(Iz_w, 32 * j, n); RB[j] = load_bt(Ir_w, 32 * j, n); HB[j] = load_bt(Ih_w, 32 * j, n); }
#pragma unroll
    for (int kt = 0; kt < 2; ++kt)
#pragma unroll
        for (int j = 0; j < 8; ++j) {
            int k = kt * 32 + q * 8 + j;
            phiB[kt][j] = (c < O_DIM && w == 0) ? (_Float16)phi_w[k * O_DIM + c] : (_Float16)0.0f;
        }

    // enc column for this lane's output col n (8 regs)
    float We[8];
#pragma unroll
    for (int j = 0; j < 8; ++j) We[j] = Wenc_w[j * 64 + n];

    const float bias_g  = Wg_b[n],  bias_z = Iz_b[n], bias_r = Ir_b[n];
    const float bias_h  = Ih_b[n],  bias_ag = Ag_b[n], bias_e = Wenc_b[n];
    const float bias_p  = (c < O_DIM) ? phi_b[c] : 0.0f;

    // this lane's batch row for x / activations: r0 + q
    const float* xrow = x + (size_t)(r0 + q) * (T_LEN * 8);

    f32x4 zero4 = {0.f, 0.f, 0.f, 0.f};

    // xt(0)
    float xt;
    {
        float4 a = *(const float4*)(xrow);
        float4 b = *(const float4*)(xrow + 4);
        float d = bias_e;
        d = __builtin_fmaf(a.x, We[0], d); d = __builtin_fmaf(a.y, We[1], d);
        d = __builtin_fmaf(a.z, We[2], d); d = __builtin_fmaf(a.w, We[3], d);
        d = __builtin_fmaf(b.x, We[4], d); d = __builtin_fmaf(b.y, We[5], d);
        d = __builtin_fmaf(b.z, We[6], d); d = __builtin_fmaf(b.w, We[7], d);
        xt = tanh_f(d);
    }

    // cross-stage accumulators
    f32x4 w_a = zero4, w_b = zero4, g_a = zero4, g_b = zero4;
    f32x4 zp_a = zero4, zp_c = zero4, rp_a = zero4, rp_c = zero4;
    f32x4 hp_a, hp_c, ap_a, ap_c, ag_a, ag_c;
    float Iv = 0.f;
    f16x8 nW0, nW1;

    __syncthreads();

#pragma unroll 1
    for (int t = 0; t < T_LEN; ++t) {
        const bool fl = ((t & 15) == 0) && (t > 0);

        // prefetch x(t+1) (drains at alpha, hidden under stage-1 work)
        int tn = (t + 1 < T_LEN) ? t + 1 : t;
        float4 xa = *(const float4*)(xrow + (size_t)tn * 8);
        float4 xb = *(const float4*)(xrow + (size_t)tn * 8 + 4);

        // ============ stage 1: W_new ============
        f16x8 sA0 = ld_af(&Al[0][0], 0), sA1 = ld_af(&Al[0][0], 1);
        w_a = MFMA(sA0, S1B[4], w_a);  w_b = MFMA(sA1, S1B[5], w_b);
        g_a = MFMA(sA0, G1B[2], g_a);  g_b = MFMA(sA1, G1B[3], g_b);
        {
            float wn = tanh_f(xt + w_a[0] + w_b[0]) * sigm_f(g_a[0] + g_b[0] + bias_g);
            Wl[4 * q][n] = (_Float16)wn;
        }
        // off-path: A-parts of z/r/h/a; action(t-1)
        zp_a = MFMA(sA0, ZB[4], zp_a);  zp_c = MFMA(sA1, ZB[5], zp_c);
        rp_a = MFMA(sA0, RB[4], rp_a);  rp_c = MFMA(sA1, RB[5], rp_c);
        hp_a = MFMA(sA0, HB[4], zero4); hp_c = MFMA(sA1, HB[5], zero4);
        ap_a = MFMA(sA0, AB[4], zero4); ap_c = MFMA(sA1, AB[5], zero4);
        if (w == 0) {
            f32x4 act = MFMA(sA0, phiB[0], zero4);
            act = MFMA(sA1, phiB[1], act);
            if (t > 0 && c < O_DIM)
                actb[q][(t - 1) & 15][c] = act[0] + bias_p;
        }
        __syncthreads();  // alpha

        // ============ stage 2: r*I (and z) ============
        nW0 = ld_af(&Wl[0][0], 0); nW1 = ld_af(&Wl[0][0], 1);
        rp_a = MFMA(nW0, RB[0], rp_a);  rp_c = MFMA(nW1, RB[1], rp_c);
        {
            float rv = sigm_f(rp_a[0] + rp_c[0] + bias_r);
            Rl[4 * q][n] = (_Float16)(rv * Iv);
        }
        zp_a = MFMA(nW0, ZB[0], zp_a);  zp_c = MFMA(nW1, ZB[1], zp_c);
        float zv = sigm_f(zp_a[0] + zp_c[0] + bias_z);
        hp_a = MFMA(nW0, HB[0], hp_a);  hp_c = MFMA(nW1, HB[1], hp_c);
        ap_a = MFMA(nW0, AB[0], ap_a);  ap_c = MFMA(nW1, AB[1], ap_c);
        ag_a = MFMA(nW0, AGB[0], zero4); ag_c = MFMA(nW1, AGB[1], zero4);
        // flush buffered actions (wave 0: lane = row*16 + slot)
        if (fl && tid < 64) {
            int row = tid >> 4, sl = tid & 15;
            float4 av = *(const float4*)(&actb[row][sl][0]);
            *(float4*)(out + (size_t)(r0 + row) * (T_LEN * O_DIM) + (t - 16 + sl) * 4) = av;
        }
        __syncthreads();  // beta

        // ============ stage 3: I_new ============
        f16x8 hR0 = ld_af(&Rl[0][0], 0), hR1 = ld_af(&Rl[0][0], 1);
        hp_a = MFMA(hR0, HB[2], hp_a);  hp_c = MFMA(hR1, HB[3], hp_c);
        {
            float hv = tanh_f(hp_a[0] + hp_c[0] + bias_h);
            Iv = __builtin_fmaf(zv, hv - Iv, Iv);
            Il[4 * q][n] = (_Float16)Iv;
        }
        // off-path: xt(t+1) from prefetched x (pure VALU)
        {
            float d = bias_e;
            d = __builtin_fmaf(xa.x, We[0], d); d = __builtin_fmaf(xa.y, We[1], d);
            d = __builtin_fmaf(xa.z, We[2], d); d = __builtin_fmaf(xa.w, We[3], d);
            d = __builtin_fmaf(xb.x, We[4], d); d = __builtin_fmaf(xb.y, We[5], d);
            d = __builtin_fmaf(xb.z, We[6], d); d = __builtin_fmaf(xb.w, We[7], d);
            xt = tanh_f(d);
        }
        __syncthreads();  // gamma

        // ============ stage 4: A_new (+ next-step partials) ============
        f16x8 nI0 = ld_af(&Il[0][0], 0), nI1 = ld_af(&Il[0][0], 1);
        ap_a = MFMA(nI0, AB[2], ap_a);  ap_c = MFMA(nI1, AB[3], ap_c);
        ag_a = MFMA(nI0, AGB[2], ag_a); ag_c = MFMA(nI1, AGB[3], ag_c);
        {
            float av = tanh_f(ap_a[0] + ap_c[0]) * sigm_f(ag_a[0] + ag_c[0] + bias_ag);
            Al[4 * q][n] = (_Float16)av;
        }
        // off-path: next step's W/I-based partials
        w_a = MFMA(nW0, S1B[0], zero4);  w_b = MFMA(nW1, S1B[1], zero4);
        w_a = MFMA(nI0, S1B[2], w_a);    w_b = MFMA(nI1, S1B[3], w_b);
        g_a = MFMA(nI0, G1B[0], zero4);  g_b = MFMA(nI1, G1B[1], zero4);
        zp_a = MFMA(nI0, ZB[2], zero4);  zp_c = MFMA(nI1, ZB[3], zero4);
        rp_a = MFMA(nI0, RB[2], zero4);  rp_c = MFMA(nI1, RB[3], zero4);
        __syncthreads();  // delta
    }

    // epilogue: action(511) + final flush (496..511)
    {
        f16x8 eA0 = ld_af(&Al[0][0], 0), eA1 = ld_af(&Al[0][0], 1);
        if (w == 0) {
            f32x4 act = MFMA(eA0, phiB[0], zero4);
            act = MFMA(eA1, phiB[1], act);
            if (c < O_DIM)
                actb[q][15][c] = act[0] + bias_p;
        }
        __syncthreads();
        if (tid < 64) {
            int row = tid >> 4, sl = tid & 15;
            float4 av = *(const float4*)(&actb[row][sl][0]);
            *(float4*)(out + (size_t)(r0 + row) * (T_LEN * O_DIM) + (496 + sl) * 4) = av;
        }
    }
}

extern "C" void kernel_launch(void* const* d_in, const int* in_sizes, int n_in,
                              void* d_out, int out_size, void* d_ws, size_t ws_size,
                              hipStream_t stream) {
    ANIMAZeroExact_86887188398421_kernel<<<dim3(256), dim3(256), 0, stream>>>(
        (const float*)d_in[0],
        (const float*)d_in[1],  (const float*)d_in[2],
        (const float*)d_in[3],  (const float*)d_in[4],  (const float*)d_in[5],
        (const float*)d_in[6],  (const float*)d_in[7],
        (const float*)d_in[8],  (const float*)d_in[9],
        (const float*)d_in[10], (const float*)d_in[11],
        (const float*)d_in[12], (const float*)d_in[13],
        (const float*)d_in[14], (const float*)d_in[15], (const float*)d_in[16],
        (const float*)d_in[17], (const float*)d_in[18],
        (const float*)d_in[19], (const float*)d_in[20],
        (float*)d_out);
}

// Round 7
// 517.995 us; speedup vs baseline: 1.5734x; 1.0867x over previous
//
#include <hip/hip_runtime.h>
#include <cstddef>
#include <cstdint>

#define T_LEN 512
#define O_DIM 4

typedef _Float16 f16x8 __attribute__((ext_vector_type(8)));
typedef float    f32x4 __attribute__((ext_vector_type(4)));

#define MFMA(a, b, c) __builtin_amdgcn_mfma_f32_16x16x32_f16((a), (b), (c), 0, 0, 0)

__device__ __forceinline__ float sigm_f(float x) {
    return __builtin_amdgcn_rcpf(1.0f + __builtin_amdgcn_exp2f(x * -1.44269504f));
}
__device__ __forceinline__ float tanh_f(float x) {
    float e = __builtin_amdgcn_exp2f(x * 2.88539008f);
    return __builtin_fmaf(-2.0f, __builtin_amdgcn_rcpf(e + 1.0f), 1.0f);
}

__device__ __forceinline__ f16x8 zf8() {
    f16x8 r;
#pragma unroll
    for (int j = 0; j < 8; ++j) r[j] = (_Float16)0.0f;
    return r;
}

// B-fragment for 16x16x32 f16 MFMA from a row-major [K x 64] fp32 matrix.
__device__ __forceinline__ f16x8 load_bt(const float* __restrict__ W, int k0, int n) {
    const int lane = threadIdx.x & 63;
    const float* p = W + (size_t)(k0 + ((lane >> 4) << 3)) * 64 + n;
    f16x8 r;
#pragma unroll
    for (int j = 0; j < 8; ++j) r[j] = (_Float16)p[(size_t)j * 64];
    return r;
}

// A-fragment from LDS state array [16][72] f16.
__device__ __forceinline__ f16x8 ld_af(const _Float16* base, int kt) {
    const int lane = threadIdx.x & 63;
    const int m = lane & 15, q = lane >> 4;
    return *(const f16x8*)(base + m * 72 + kt * 32 + q * 8);
}

// 256 threads = 4 waves, 4 valid batch rows per block at tile rows {0,4,8,12}.
// Cross-segment pipelining: every segment's post-barrier ds_read latency window
// is filled with MFMAs whose operands were read in a PREVIOUS segment:
//   seg1(reads sA): fillers z/r I-terms (nI from last seg4)
//   seg2(reads nW): fillers z/r/h/ap A-terms + phi (sA from seg1)
//   seg3(reads hR): fillers h/ap/ag/w W-terms (nW from seg2)
//   seg4(reads nI): trailing w/g I-terms feed next step's seg1
// x comes from a 16-step LDS tile (no per-step global ops -> no vmcnt drains).
__global__ __launch_bounds__(256, 1) void ANIMAZeroExact_86887188398421_kernel(
    const float* __restrict__ x,
    const float* __restrict__ Wenc_w, const float* __restrict__ Wenc_b,
    const float* __restrict__ WfW, const float* __restrict__ WfI, const float* __restrict__ WfA,
    const float* __restrict__ Wg_w, const float* __restrict__ Wg_b,
    const float* __restrict__ Iz_w, const float* __restrict__ Iz_b,
    const float* __restrict__ Ir_w, const float* __restrict__ Ir_b,
    const float* __restrict__ Ih_w, const float* __restrict__ Ih_b,
    const float* __restrict__ AfW, const float* __restrict__ AfI, const float* __restrict__ AfA,
    const float* __restrict__ Ag_w, const float* __restrict__ Ag_b,
    const float* __restrict__ phi_w, const float* __restrict__ phi_b,
    float* __restrict__ out)
{
    __shared__ __align__(16) _Float16 Wl[16][72];
    __shared__ __align__(16) _Float16 Il[16][72];
    __shared__ __align__(16) _Float16 Al[16][72];
    __shared__ __align__(16) _Float16 Rl[16][72];
    __shared__ __align__(16) float xtile[4 * 132 + 4];  // [row][slot*8], row stride 132 (bank-skewed)
    __shared__ __align__(16) float actb[4][16][4];      // [row][slot][o]

    const int tid  = threadIdx.x;
    const int w    = tid >> 6;
    const int lane = tid & 63;
    const int q    = lane >> 4;
    const int c    = lane & 15;
    const int n    = w * 16 + c;
    const int r0   = blockIdx.x * 4;

    // zero states; junk tile rows stay zero forever
    for (int i = tid; i < 16 * 72; i += 256) {
        (&Wl[0][0])[i] = (_Float16)0.0f; (&Il[0][0])[i] = (_Float16)0.0f;
        (&Al[0][0])[i] = (_Float16)0.0f; (&Rl[0][0])[i] = (_Float16)0.0f;
    }

    // ---- resident weight B-fragments ----
    f16x8 S1B[6], G1B[4], ZB[6], RB[6], HB[6], AB[6], AGB[4], phiB[2];
#pragma unroll
    for (int j = 0; j < 2; ++j) {
        S1B[j] = load_bt(WfW, 32 * j, n);  S1B[2 + j] = load_bt(WfI, 32 * j, n);  S1B[4 + j] = load_bt(WfA, 32 * j, n);
        AB[j]  = load_bt(AfW, 32 * j, n);  AB[2 + j]  = load_bt(AfI, 32 * j, n);  AB[4 + j]  = load_bt(AfA, 32 * j, n);
    }
#pragma unroll
    for (int j = 0; j < 4; ++j) { G1B[j] = load_bt(Wg_w, 32 * j, n); AGB[j] = load_bt(Ag_w, 32 * j, n); }
#pragma unroll
    for (int j = 0; j < 6; ++j) { ZB[j] = load_bt(Iz_w, 32 * j, n); RB[j] = load_bt(Ir_w, 32 * j, n); HB[j] = load_bt(Ih_w, 32 * j, n); }
#pragma unroll
    for (int kt = 0; kt < 2; ++kt)
#pragma unroll
        for (int j = 0; j < 8; ++j) {
            int k = kt * 32 + q * 8 + j;
            phiB[kt][j] = (c < O_DIM && w == 0) ? (_Float16)phi_w[k * O_DIM + c] : (_Float16)0.0f;
        }

    // enc column for this lane's output col n
    float We[8];
#pragma unroll
    for (int j = 0; j < 8; ++j) We[j] = Wenc_w[j * 64 + n];

    const float bias_g  = Wg_b[n],  bias_z = Iz_b[n], bias_r = Ir_b[n];
    const float bias_h  = Ih_b[n],  bias_ag = Ag_b[n], bias_e = Wenc_b[n];
    const float bias_p  = (c < O_DIM) ? phi_b[c] : 0.0f;

    f32x4 zero4 = {0.f, 0.f, 0.f, 0.f};

    // prologue: stage x-tile slots 0..15 = x(1..16); compute xt(0) directly
    if (tid < 64) {
        const int row = tid >> 4, su = tid & 15;
        const float* xg = x + (size_t)(r0 + row) * (T_LEN * 8) + (1 + su) * 8;
        float4 a = *(const float4*)(xg);
        float4 b = *(const float4*)(xg + 4);
        float* d = &xtile[row * 132 + su * 8];
        *(float4*)d = a; *(float4*)(d + 4) = b;
    }
    float xt;
    {
        const float* xg = x + (size_t)(r0 + q) * (T_LEN * 8);
        float4 a = *(const float4*)(xg);
        float4 b = *(const float4*)(xg + 4);
        float d = bias_e;
        d = __builtin_fmaf(a.x, We[0], d); d = __builtin_fmaf(a.y, We[1], d);
        d = __builtin_fmaf(a.z, We[2], d); d = __builtin_fmaf(a.w, We[3], d);
        d = __builtin_fmaf(b.x, We[4], d); d = __builtin_fmaf(b.y, We[5], d);
        d = __builtin_fmaf(b.z, We[6], d); d = __builtin_fmaf(b.w, We[7], d);
        xt = tanh_f(d);
    }

    // loop-carried
    f16x8 nI0 = zf8(), nI1 = zf8(), nW0, nW1;
    f32x4 w_a = zero4, w_b = zero4, g_a = zero4, g_b = zero4;
    f32x4 zp_a, zp_c, rp_a, rp_c, hp_a, hp_c, ap_a, ap_c, ag_a, ag_c;
    float Iv = 0.f;

    __syncthreads();

#pragma unroll 1
    for (int t = 0; t < T_LEN; ++t) {
        const bool fl = ((t & 15) == 0) && (t > 0);

        // ============ seg1: W_new ============
        f16x8 sA0 = ld_af(&Al[0][0], 0), sA1 = ld_af(&Al[0][0], 1);
        float4 xla = {0,0,0,0}, xlb = {0,0,0,0};
        if (fl && tid < 64) {   // flush-period x loads (drain at alpha, once/16 steps)
            const int row = tid >> 4, su = tid & 15;
            int off = (t + 1 + su) * 8;
            if (off > T_LEN * 8 - 8) off = T_LEN * 8 - 8;
            const float* xg = x + (size_t)(r0 + row) * (T_LEN * 8) + off;
            xla = *(const float4*)(xg); xlb = *(const float4*)(xg + 4);
        }
        // filler: z/r I-terms (nI = I(t-1), read last seg4)
        zp_a = MFMA(nI0, ZB[2], zero4); zp_c = MFMA(nI1, ZB[3], zero4);
        rp_a = MFMA(nI0, RB[2], zero4); rp_c = MFMA(nI1, RB[3], zero4);
        // critical: A-terms of W_in / Wg, then activation + publish
        w_a = MFMA(sA0, S1B[4], w_a);  w_b = MFMA(sA1, S1B[5], w_b);
        g_a = MFMA(sA0, G1B[2], g_a);  g_b = MFMA(sA1, G1B[3], g_b);
        {
            float wn = tanh_f(xt + w_a[0] + w_b[0]) * sigm_f(g_a[0] + g_b[0] + bias_g);
            Wl[4 * q][n] = (_Float16)wn;
        }
        __syncthreads();  // alpha

        // ============ seg2: r*I ============
        nW0 = ld_af(&Wl[0][0], 0); nW1 = ld_af(&Wl[0][0], 1);
        // filler: A-terms (sA from seg1 — ready)
        hp_a = MFMA(sA0, HB[4], zero4); hp_c = MFMA(sA1, HB[5], zero4);
        ap_a = MFMA(sA0, AB[4], zero4); ap_c = MFMA(sA1, AB[5], zero4);
        zp_a = MFMA(sA0, ZB[4], zp_a);  zp_c = MFMA(sA1, ZB[5], zp_c);
        rp_a = MFMA(sA0, RB[4], rp_a);  rp_c = MFMA(sA1, RB[5], rp_c);
        if (w == 0) {   // action(t-1) = A(t-1) @ phi
            f32x4 act = MFMA(sA0, phiB[0], zero4);
            act = MFMA(sA1, phiB[1], act);
            if (t > 0 && c < O_DIM)
                actb[q][(t - 1) & 15][c] = act[0] + bias_p;
        }
        // critical: r W-term, activation, publish rI
        rp_a = MFMA(nW0, RB[0], rp_a);  rp_c = MFMA(nW1, RB[1], rp_c);
        {
            float rv = sigm_f(rp_a[0] + rp_c[0] + bias_r);
            Rl[4 * q][n] = (_Float16)(rv * Iv);
        }
        // z W-term (consumed next segment)
        zp_a = MFMA(nW0, ZB[0], zp_a);  zp_c = MFMA(nW1, ZB[1], zp_c);
        // flush-period: publish new x-tile slots
        if (fl && tid < 64) {
            const int row = tid >> 4, su = tid & 15;
            float* d = &xtile[row * 132 + su * 8];
            *(float4*)d = xla; *(float4*)(d + 4) = xlb;
        }
        __syncthreads();  // beta

        // ============ seg3: I_new ============
        f16x8 hR0 = ld_af(&Rl[0][0], 0), hR1 = ld_af(&Rl[0][0], 1);
        // x for xt(t+1): broadcast LDS read (independent of states)
        const float* xs = &xtile[q * 132 + (t & 15) * 8];
        float4 qa = *(const float4*)xs;
        float4 qb = *(const float4*)(xs + 4);
        // filler: W-terms (nW from seg2 — ready)
        hp_a = MFMA(nW0, HB[0], hp_a);  hp_c = MFMA(nW1, HB[1], hp_c);
        ap_a = MFMA(nW0, AB[0], ap_a);  ap_c = MFMA(nW1, AB[1], ap_c);
        ag_a = MFMA(nW0, AGB[0], zero4); ag_c = MFMA(nW1, AGB[1], zero4);
        w_a  = MFMA(nW0, S1B[0], zero4); w_b = MFMA(nW1, S1B[1], zero4);
        float zv = sigm_f(zp_a[0] + zp_c[0] + bias_z);
        // flush-period: store 16 buffered actions (actb slot 15 written seg2, beta-ordered)
        if (fl && tid < 64) {
            const int row = tid >> 4, sl = tid & 15;
            float4 av = *(const float4*)(&actb[row][sl][0]);
            *(float4*)(out + (size_t)(r0 + row) * (T_LEN * O_DIM) + (t - 16 + sl) * 4) = av;
        }
        // critical: h rI-term, activation, publish I_new
        hp_a = MFMA(hR0, HB[2], hp_a);  hp_c = MFMA(hR1, HB[3], hp_c);
        {
            float hv = tanh_f(hp_a[0] + hp_c[0] + bias_h);
            Iv = __builtin_fmaf(zv, hv - Iv, Iv);
            Il[4 * q][n] = (_Float16)Iv;
        }
        __syncthreads();  // gamma

        // ============ seg4: A_new ============
        nI0 = ld_af(&Il[0][0], 0); nI1 = ld_af(&Il[0][0], 1);
        // filler: xt(t+1) dot (pure VALU, independent)
        {
            float d = bias_e;
            d = __builtin_fmaf(qa.x, We[0], d); d = __builtin_fmaf(qa.y, We[1], d);
            d = __builtin_fmaf(qa.z, We[2], d); d = __builtin_fmaf(qa.w, We[3], d);
            d = __builtin_fmaf(qb.x, We[4], d); d = __builtin_fmaf(qb.y, We[5], d);
            d = __builtin_fmaf(qb.z, We[6], d); d = __builtin_fmaf(qb.w, We[7], d);
            xt = tanh_f(d);
        }
        // critical: A I-terms, activation, publish A_new
        ap_a = MFMA(nI0, AB[2], ap_a);  ap_c = MFMA(nI1, AB[3], ap_c);
        ag_a = MFMA(nI0, AGB[2], ag_a); ag_c = MFMA(nI1, AGB[3], ag_c);
        {
            float av = tanh_f(ap_a[0] + ap_c[0]) * sigm_f(ag_a[0] + ag_c[0] + bias_ag);
            Al[4 * q][n] = (_Float16)av;
        }
        // trailing: next step's W_in/Wg I-terms (feed seg1 fillers/critical)
        w_a = MFMA(nI0, S1B[2], w_a);   w_b = MFMA(nI1, S1B[3], w_b);
        g_a = MFMA(nI0, G1B[0], zero4); g_b = MFMA(nI1, G1B[1], zero4);
        __syncthreads();  // delta
    }

    // epilogue: action(511) + final flush (496..511)
    {
        f16x8 eA0 = ld_af(&Al[0][0], 0), eA1 = ld_af(&Al[0][0], 1);
        if (w == 0) {
            f32x4 act = MFMA(eA0, phiB[0], zero4);
            act = MFMA(eA1, phiB[1], act);
            if (c < O_DIM)
                actb[q][15][c] = act[0] + bias_p;
        }
        __syncthreads();
        if (tid < 64) {
            const int row = tid >> 4, sl = tid & 15;
            float4 av = *(const float4*)(&actb[row][sl][0]);
            *(float4*)(out + (size_t)(r0 + row) * (T_LEN * O_DIM) + (496 + sl) * 4) = av;
        }
    }
}

extern "C" void kernel_launch(void* const* d_in, const int* in_sizes, int n_in,
                              void* d_out, int out_size, void* d_ws, size_t ws_size,
                              hipStream_t stream) {
    ANIMAZeroExact_86887188398421_kernel<<<dim3(256), dim3(256), 0, stream>>>(
        (const float*)d_in[0],
        (const float*)d_in[1],  (const float*)d_in[2],
        (const float*)d_in[3],  (const float*)d_in[4],  (const float*)d_in[5],
        (const float*)d_in[6],  (const float*)d_in[7],
        (const float*)d_in[8],  (const float*)d_in[9],
        (const float*)d_in[10], (const float*)d_in[11],
        (const float*)d_in[12], (const float*)d_in[13],
        (const float*)d_in[14], (const float*)d_in[15], (const float*)d_in[16],
        (const float*)d_in[17], (const float*)d_in[18],
        (const float*)d_in[19], (const float*)d_in[20],
        (float*)d_out);
}

// Round 8
// 496.706 us; speedup vs baseline: 1.6409x; 1.0429x over previous
//
#include <hip/hip_runtime.h>
#include <cstddef>
#include <cstdint>

#define T_LEN 512
#define O_DIM 4

typedef _Float16 f16x8 __attribute__((ext_vector_type(8)));
typedef float    f32x4 __attribute__((ext_vector_type(4)));

#define MFMA(a, b, c) __builtin_amdgcn_mfma_f32_16x16x32_f16((a), (b), (c), 0, 0, 0)

__device__ __forceinline__ float sigm_f(float x) {
    return __builtin_amdgcn_rcpf(1.0f + __builtin_amdgcn_exp2f(x * -1.44269504f));
}
__device__ __forceinline__ float tanh_f(float x) {
    float e = __builtin_amdgcn_exp2f(x * 2.88539008f);
    return __builtin_fmaf(-2.0f, __builtin_amdgcn_rcpf(e + 1.0f), 1.0f);
}

__device__ __forceinline__ f16x8 zf8() {
    f16x8 r;
#pragma unroll
    for (int j = 0; j < 8; ++j) r[j] = (_Float16)0.0f;
    return r;
}

// B-fragment for 16x16x32 f16 MFMA from a row-major [K x 64] fp32 matrix.
__device__ __forceinline__ f16x8 load_bt(const float* __restrict__ W, int k0, int n) {
    const int lane = threadIdx.x & 63;
    const float* p = W + (size_t)(k0 + ((lane >> 4) << 3)) * 64 + n;
    f16x8 r;
#pragma unroll
    for (int j = 0; j < 8; ++j) r[j] = (_Float16)p[(size_t)j * 64];
    return r;
}

// A-fragment from LDS state array [16][72] f16.
__device__ __forceinline__ f16x8 ld_af(const _Float16* base, int kt) {
    const int lane = threadIdx.x & 63;
    const int m = lane & 15, q = lane >> 4;
    return *(const f16x8*)(base + m * 72 + kt * 32 + q * 8);
}

// 256 threads = 4 waves, 4 valid batch rows at tile rows {0,4,8,12}.
// Scheduling discipline per segment:
//   - EARLY fillers (operands from a PREVIOUS segment's read) cover this
//     segment's ds_read latency,
//   - critical MFMAs chain only onto accumulators whose last write completed
//     >=1 barrier earlier,
//   - LATE fillers issue after the critical publish and grind through the
//     barrier into the NEXT segment's read window (MFMA doesn't block s_barrier).
// phi/action rotates across waves (w == t&3) to avoid wave-0 barrier skew.
__global__ __launch_bounds__(256, 1) void ANIMAZeroExact_86887188398421_kernel(
    const float* __restrict__ x,
    const float* __restrict__ Wenc_w, const float* __restrict__ Wenc_b,
    const float* __restrict__ WfW, const float* __restrict__ WfI, const float* __restrict__ WfA,
    const float* __restrict__ Wg_w, const float* __restrict__ Wg_b,
    const float* __restrict__ Iz_w, const float* __restrict__ Iz_b,
    const float* __restrict__ Ir_w, const float* __restrict__ Ir_b,
    const float* __restrict__ Ih_w, const float* __restrict__ Ih_b,
    const float* __restrict__ AfW, const float* __restrict__ AfI, const float* __restrict__ AfA,
    const float* __restrict__ Ag_w, const float* __restrict__ Ag_b,
    const float* __restrict__ phi_w, const float* __restrict__ phi_b,
    float* __restrict__ out)
{
    __shared__ __align__(16) _Float16 Wl[16][72];
    __shared__ __align__(16) _Float16 Il[16][72];
    __shared__ __align__(16) _Float16 Al[16][72];
    __shared__ __align__(16) _Float16 Rl[16][72];
    __shared__ __align__(16) float xtile[4 * 132 + 4];
    __shared__ __align__(16) float actb[4][16][4];

    const int tid  = threadIdx.x;
    const int w    = tid >> 6;
    const int lane = tid & 63;
    const int q    = lane >> 4;
    const int c    = lane & 15;
    const int n    = w * 16 + c;
    const int r0   = blockIdx.x * 4;

    for (int i = tid; i < 16 * 72; i += 256) {
        (&Wl[0][0])[i] = (_Float16)0.0f; (&Il[0][0])[i] = (_Float16)0.0f;
        (&Al[0][0])[i] = (_Float16)0.0f; (&Rl[0][0])[i] = (_Float16)0.0f;
    }

    // ---- resident weight B-fragments ----
    f16x8 S1B[6], G1B[4], ZB[6], RB[6], HB[6], AB[6], AGB[4], phiB[2];
#pragma unroll
    for (int j = 0; j < 2; ++j) {
        S1B[j] = load_bt(WfW, 32 * j, n);  S1B[2 + j] = load_bt(WfI, 32 * j, n);  S1B[4 + j] = load_bt(WfA, 32 * j, n);
        AB[j]  = load_bt(AfW, 32 * j, n);  AB[2 + j]  = load_bt(AfI, 32 * j, n);  AB[4 + j]  = load_bt(AfA, 32 * j, n);
    }
#pragma unroll
    for (int j = 0; j < 4; ++j) { G1B[j] = load_bt(Wg_w, 32 * j, n); AGB[j] = load_bt(Ag_w, 32 * j, n); }
#pragma unroll
    for (int j = 0; j < 6; ++j) { ZB[j] = load_bt(Iz_w, 32 * j, n); RB[j] = load_bt(Ir_w, 32 * j, n); HB[j] = load_bt(Ih_w, 32 * j, n); }
    // phi fragment in ALL waves (rotation); cols >= O_DIM zeroed
#pragma unroll
    for (int kt = 0; kt < 2; ++kt)
#pragma unroll
        for (int j = 0; j < 8; ++j) {
            int k = kt * 32 + q * 8 + j;
            phiB[kt][j] = (c < O_DIM) ? (_Float16)phi_w[k * O_DIM + c] : (_Float16)0.0f;
        }

    float We[8];
#pragma unroll
    for (int j = 0; j < 8; ++j) We[j] = Wenc_w[j * 64 + n];

    const float bias_g  = Wg_b[n],  bias_z = Iz_b[n], bias_r = Ir_b[n];
    const float bias_h  = Ih_b[n],  bias_ag = Ag_b[n], bias_e = Wenc_b[n];
    const float bias_p  = (c < O_DIM) ? phi_b[c] : 0.0f;

    f32x4 zero4 = {0.f, 0.f, 0.f, 0.f};

    // prologue: stage x-tile slots 0..15 = x(1..16); xt(0) direct
    if (tid < 64) {
        const int row = tid >> 4, su = tid & 15;
        const float* xg = x + (size_t)(r0 + row) * (T_LEN * 8) + (1 + su) * 8;
        float4 a = *(const float4*)(xg);
        float4 b = *(const float4*)(xg + 4);
        float* d = &xtile[row * 132 + su * 8];
        *(float4*)d = a; *(float4*)(d + 4) = b;
    }
    float xt;
    {
        const float* xg = x + (size_t)(r0 + q) * (T_LEN * 8);
        float4 a = *(const float4*)(xg);
        float4 b = *(const float4*)(xg + 4);
        float d = bias_e;
        d = __builtin_fmaf(a.x, We[0], d); d = __builtin_fmaf(a.y, We[1], d);
        d = __builtin_fmaf(a.z, We[2], d); d = __builtin_fmaf(a.w, We[3], d);
        d = __builtin_fmaf(b.x, We[4], d); d = __builtin_fmaf(b.y, We[5], d);
        d = __builtin_fmaf(b.z, We[6], d); d = __builtin_fmaf(b.w, We[7], d);
        xt = tanh_f(d);
    }

    // loop-carried accumulators (all zero-init = value for states(-1)=0)
    f32x4 w_a = zero4, w_b = zero4, g_a = zero4, g_b = zero4;
    f32x4 zp_a = zero4, zp_c = zero4, rp_a = zero4, rp_c = zero4;
    f32x4 hp_a, hp_c, ap_a, ap_c, ag_a, ag_c;
    float Iv = 0.f;
    f16x8 nW0, nW1;

    __syncthreads();

#pragma unroll 1
    for (int t = 0; t < T_LEN; ++t) {
        const bool fl = ((t & 15) == 0) && (t > 0);
        const int tw = t & 3;

        // ============ seg1: W_new ============
        // read window covered by prev seg4's late fillers still in the pipe
        f16x8 sA0 = ld_af(&Al[0][0], 0), sA1 = ld_af(&Al[0][0], 1);
        float4 xla = {0,0,0,0}, xlb = {0,0,0,0};
        if (fl && tid < 64) {
            const int row = tid >> 4, su = tid & 15;
            int off = (t + 1 + su) * 8;
            if (off > T_LEN * 8 - 8) off = T_LEN * 8 - 8;
            const float* xg = x + (size_t)(r0 + row) * (T_LEN * 8) + off;
            xla = *(const float4*)(xg); xlb = *(const float4*)(xg + 4);
        }
        // critical: w/g accumulators last touched in prev seg4-late (1 barrier ago)
        w_a = MFMA(sA0, S1B[4], w_a);  w_b = MFMA(sA1, S1B[5], w_b);
        g_a = MFMA(sA0, G1B[2], g_a);  g_b = MFMA(sA1, G1B[3], g_b);
        {
            float wn = tanh_f(xt + w_a[0] + w_b[0]) * sigm_f(g_a[0] + g_b[0] + bias_g);
            Wl[4 * q][n] = (_Float16)wn;
        }
        // late fillers: z/r A-terms (r's A-term must be 1 barrier before seg2's critical r)
        zp_a = MFMA(sA0, ZB[4], zp_a);  zp_c = MFMA(sA1, ZB[5], zp_c);
        rp_a = MFMA(sA0, RB[4], rp_a);  rp_c = MFMA(sA1, RB[5], rp_c);
        __syncthreads();  // alpha

        // ============ seg2: r*I ============
        nW0 = ld_af(&Wl[0][0], 0); nW1 = ld_af(&Wl[0][0], 1);
        // early fillers (sA-based, fresh accumulators) cover the nW read
        hp_a = MFMA(sA0, HB[4], zero4); hp_c = MFMA(sA1, HB[5], zero4);
        ap_a = MFMA(sA0, AB[4], zero4); ap_c = MFMA(sA1, AB[5], zero4);
        if (w == tw) {   // action(t-1) = A(t-1) @ phi, rotating wave
            f32x4 act = MFMA(sA0, phiB[0], zero4);
            act = MFMA(sA1, phiB[1], act);
            if (t > 0 && c < O_DIM)
                actb[q][(t - 1) & 15][c] = act[0] + bias_p;
        }
        // critical: rp last touched seg1-late (1 barrier ago)
        rp_a = MFMA(nW0, RB[0], rp_a);  rp_c = MFMA(nW1, RB[1], rp_c);
        {
            float rv = sigm_f(rp_a[0] + rp_c[0] + bias_r);
            Rl[4 * q][n] = (_Float16)(rv * Iv);
        }
        // late fillers (nW-based): grind through beta into seg3's read window
        zp_a = MFMA(nW0, ZB[0], zp_a);  zp_c = MFMA(nW1, ZB[1], zp_c);
        hp_a = MFMA(nW0, HB[0], hp_a);  hp_c = MFMA(nW1, HB[1], hp_c);
        w_a  = MFMA(nW0, S1B[0], zero4); w_b = MFMA(nW1, S1B[1], zero4);
        if (fl && tid < 64) {
            const int row = tid >> 4, su = tid & 15;
            float* d = &xtile[row * 132 + su * 8];
            *(float4*)d = xla; *(float4*)(d + 4) = xlb;
        }
        __syncthreads();  // beta

        // ============ seg3: I_new ============
        f16x8 hR0 = ld_af(&Rl[0][0], 0), hR1 = ld_af(&Rl[0][0], 1);
        const float* xs = &xtile[q * 132 + (t & 15) * 8];
        float4 qa = *(const float4*)xs;
        float4 qb = *(const float4*)(xs + 4);
        // early fillers (nW-based) + VALU cover the hR read
        ap_a = MFMA(nW0, AB[0], ap_a);  ap_c = MFMA(nW1, AB[1], ap_c);
        float zv = sigm_f(zp_a[0] + zp_c[0] + bias_z);
        float xtn;
        {
            float d = bias_e;
            d = __builtin_fmaf(qa.x, We[0], d); d = __builtin_fmaf(qa.y, We[1], d);
            d = __builtin_fmaf(qa.z, We[2], d); d = __builtin_fmaf(qa.w, We[3], d);
            d = __builtin_fmaf(qb.x, We[4], d); d = __builtin_fmaf(qb.y, We[5], d);
            d = __builtin_fmaf(qb.z, We[6], d); d = __builtin_fmaf(qb.w, We[7], d);
            xtn = tanh_f(d);
        }
        if (fl && tid < 64) {
            const int row = tid >> 4, sl = tid & 15;
            float4 av = *(const float4*)(&actb[row][sl][0]);
            *(float4*)(out + (size_t)(r0 + row) * (T_LEN * O_DIM) + (t - 16 + sl) * 4) = av;
        }
        // critical: hp last touched seg2-late (1 barrier ago)
        hp_a = MFMA(hR0, HB[2], hp_a);  hp_c = MFMA(hR1, HB[3], hp_c);
        {
            float hv = tanh_f(hp_a[0] + hp_c[0] + bias_h);
            Iv = __builtin_fmaf(zv, hv - Iv, Iv);
            Il[4 * q][n] = (_Float16)Iv;
        }
        // late fillers (nW-based, fresh): grind through gamma into seg4's read window
        ag_a = MFMA(nW0, AGB[0], zero4); ag_c = MFMA(nW1, AGB[1], zero4);
        __syncthreads();  // gamma

        // ============ seg4: A_new ============
        f16x8 nI0 = ld_af(&Il[0][0], 0), nI1 = ld_af(&Il[0][0], 1);
        // critical: ap last touched seg3-early, ag seg3-late (completed by now)
        ap_a = MFMA(nI0, AB[2], ap_a);  ap_c = MFMA(nI1, AB[3], ap_c);
        ag_a = MFMA(nI0, AGB[2], ag_a); ag_c = MFMA(nI1, AGB[3], ag_c);
        {
            float av = tanh_f(ap_a[0] + ap_c[0]) * sigm_f(ag_a[0] + ag_c[0] + bias_ag);
            Al[4 * q][n] = (_Float16)av;
        }
        // late fillers (nI-based): next step's W/Wg/z/r I-terms; grind through delta
        // into seg1's read window
        w_a = MFMA(nI0, S1B[2], w_a);   w_b = MFMA(nI1, S1B[3], w_b);
        g_a = MFMA(nI0, G1B[0], zero4); g_b = MFMA(nI1, G1B[1], zero4);
        zp_a = MFMA(nI0, ZB[2], zero4); zp_c = MFMA(nI1, ZB[3], zero4);
        rp_a = MFMA(nI0, RB[2], zero4); rp_c = MFMA(nI1, RB[3], zero4);
        xt = xtn;
        __syncthreads();  // delta
    }

    // epilogue: action(511) + final flush (496..511)
    {
        f16x8 eA0 = ld_af(&Al[0][0], 0), eA1 = ld_af(&Al[0][0], 1);
        if (w == 0) {
            f32x4 act = MFMA(eA0, phiB[0], zero4);
            act = MFMA(eA1, phiB[1], act);
            if (c < O_DIM)
                actb[q][15][c] = act[0] + bias_p;
        }
        __syncthreads();
        if (tid < 64) {
            const int row = tid >> 4, sl = tid & 15;
            float4 av = *(const float4*)(&actb[row][sl][0]);
            *(float4*)(out + (size_t)(r0 + row) * (T_LEN * O_DIM) + (496 + sl) * 4) = av;
        }
    }
}

extern "C" void kernel_launch(void* const* d_in, const int* in_sizes, int n_in,
                              void* d_out, int out_size, void* d_ws, size_t ws_size,
                              hipStream_t stream) {
    ANIMAZeroExact_86887188398421_kernel<<<dim3(256), dim3(256), 0, stream>>>(
        (const float*)d_in[0],
        (const float*)d_in[1],  (const float*)d_in[2],
        (const float*)d_in[3],  (const float*)d_in[4],  (const float*)d_in[5],
        (const float*)d_in[6],  (const float*)d_in[7],
        (const float*)d_in[8],  (const float*)d_in[9],
        (const float*)d_in[10], (const float*)d_in[11],
        (const float*)d_in[12], (const float*)d_in[13],
        (const float*)d_in[14], (const float*)d_in[15], (const float*)d_in[16],
        (const float*)d_in[17], (const float*)d_in[18],
        (const float*)d_in[19], (const float*)d_in[20],
        (float*)d_out);
}